// Round 1
// baseline (2509.628 us; speedup 1.0000x reference)
//
#include <hip/hip_runtime.h>
#include <cstdint>
#include <cstddef>

#define NEG_SLOPE 0.2f

// ---- float atomic-max via order-preserving unsigned encoding ----
__device__ __forceinline__ unsigned encf(float f) {
  unsigned u = __float_as_uint(f);
  return (u & 0x80000000u) ? ~u : (u | 0x80000000u);
}
__device__ __forceinline__ float decf(unsigned u) {
  return (u & 0x80000000u) ? __uint_as_float(u ^ 0x80000000u) : __uint_as_float(~u);
}

__device__ __forceinline__ float lrelu(float v) { return v > 0.0f ? v : NEG_SLOPE * v; }

// ---- GEMM: Y[N,128] = X[N,128] @ W[128,128], fp32 ----
// 64 rows/block, 256 threads, each thread computes 8 rows x 4 cols.
// LDS x-tile stride 132 floats to break stride-128 bank aliasing.
__global__ __launch_bounds__(256) void gemm128(const float* __restrict__ X,
                                               const float* __restrict__ W,
                                               float* __restrict__ Y, int N) {
  __shared__ float xs[64 * 132];
  const int tid = threadIdx.x;
  const int rowBase = blockIdx.x * 64;
  const int rowsHere = min(64, N - rowBase);
  for (int i = tid; i < 64 * 32; i += 256) {
    int r = i >> 5, c4 = i & 31;
    float4 v = make_float4(0.f, 0.f, 0.f, 0.f);
    if (r < rowsHere) v = *(const float4*)(X + (size_t)(rowBase + r) * 128 + c4 * 4);
    *(float4*)(xs + r * 132 + c4 * 4) = v;
  }
  __syncthreads();
  const int j0 = (tid & 31) * 4;
  const int r0 = (tid >> 5) * 8;
  float4 acc[8];
#pragma unroll
  for (int r = 0; r < 8; ++r) acc[r] = make_float4(0.f, 0.f, 0.f, 0.f);
  for (int k0 = 0; k0 < 128; k0 += 4) {
    float4 w0 = *(const float4*)(W + (size_t)(k0 + 0) * 128 + j0);
    float4 w1 = *(const float4*)(W + (size_t)(k0 + 1) * 128 + j0);
    float4 w2 = *(const float4*)(W + (size_t)(k0 + 2) * 128 + j0);
    float4 w3 = *(const float4*)(W + (size_t)(k0 + 3) * 128 + j0);
#pragma unroll
    for (int r = 0; r < 8; ++r) {
      float4 xv = *(const float4*)(xs + (r0 + r) * 132 + k0);
      acc[r].x += xv.x * w0.x + xv.y * w1.x + xv.z * w2.x + xv.w * w3.x;
      acc[r].y += xv.x * w0.y + xv.y * w1.y + xv.z * w2.y + xv.w * w3.y;
      acc[r].z += xv.x * w0.z + xv.y * w1.z + xv.z * w2.z + xv.w * w3.z;
      acc[r].w += xv.x * w0.w + xv.y * w1.w + xv.z * w2.w + xv.w * w3.w;
    }
  }
#pragma unroll
  for (int r = 0; r < 8; ++r) {
    int row = r0 + r;
    if (row < rowsHere) *(float4*)(Y + (size_t)(rowBase + row) * 128 + j0) = acc[r];
  }
}

// ---- alpha_src/alpha_dst for H=4, C=32: 32-lane group per (n,h) ----
__global__ __launch_bounds__(256) void alphas_h4(const float* __restrict__ Hm,
    const float* __restrict__ Asrc, const float* __restrict__ Adst,
    float* __restrict__ AS, float* __restrict__ AD, int N) {
  const int tid = threadIdx.x;
  const int g = blockIdx.x * 8 + (tid >> 5);  // g = n*4 + h
  if (g >= N * 4) return;
  const int lane = tid & 31;
  const int h = g & 3;
  float v = Hm[(size_t)g * 32 + lane];
  float as = v * Asrc[h * 32 + lane];
  float ad = v * Adst[h * 32 + lane];
#pragma unroll
  for (int o = 16; o >= 1; o >>= 1) {
    as += __shfl_xor(as, o, 64);
    ad += __shfl_xor(ad, o, 64);
  }
  if (lane == 0) { AS[g] = as; AD[g] = ad; }
}

// ---- alpha_src/alpha_dst for H=1, C=128: 64-lane group per node ----
__global__ __launch_bounds__(256) void alphas_h1(const float* __restrict__ Hm,
    const float* __restrict__ Asrc, const float* __restrict__ Adst,
    float* __restrict__ AS, float* __restrict__ AD, int N) {
  const int tid = threadIdx.x;
  const int n = blockIdx.x * 4 + (tid >> 6);
  if (n >= N) return;
  const int lane = tid & 63;
  float v0 = Hm[(size_t)n * 128 + lane];
  float v1 = Hm[(size_t)n * 128 + 64 + lane];
  float as = v0 * Asrc[lane] + v1 * Asrc[64 + lane];
  float ad = v0 * Adst[lane] + v1 * Adst[64 + lane];
#pragma unroll
  for (int o = 32; o >= 1; o >>= 1) {
    as += __shfl_xor(as, o, 64);
    ad += __shfl_xor(ad, o, 64);
  }
  if (lane == 0) { AS[n] = as; AD[n] = ad; }
}

// ---- edge pass 1: e = leakyrelu(as[src]+ad[dst]); store; atomicMax segmax ----
template <int H>
__global__ __launch_bounds__(256) void epass1(const int* __restrict__ ei, int E, int Etot,
    const float* __restrict__ AS, const float* __restrict__ AD,
    float* __restrict__ EB, unsigned* __restrict__ M) {
  const int e = blockIdx.x * 256 + threadIdx.x;
  if (e >= Etot) return;
  int s, d;
  if (e < E) { s = ei[e]; d = ei[E + e]; } else { s = e - E; d = s; }
  if (H == 4) {
    float4 as = *(const float4*)(AS + (size_t)s * 4);
    float4 ad = *(const float4*)(AD + (size_t)d * 4);
    float4 ev;
    ev.x = lrelu(as.x + ad.x);
    ev.y = lrelu(as.y + ad.y);
    ev.z = lrelu(as.z + ad.z);
    ev.w = lrelu(as.w + ad.w);
    *(float4*)(EB + (size_t)e * 4) = ev;
    atomicMax(&M[d * 4 + 0], encf(ev.x));
    atomicMax(&M[d * 4 + 1], encf(ev.y));
    atomicMax(&M[d * 4 + 2], encf(ev.z));
    atomicMax(&M[d * 4 + 3], encf(ev.w));
  } else {
    float v = lrelu(AS[s] + AD[d]);
    EB[e] = v;
    atomicMax(&M[d], encf(v));
  }
}

// ---- edge pass 2: denom[dst] += exp(e - m[dst]) ----
template <int H>
__global__ __launch_bounds__(256) void epass2(const int* __restrict__ ei, int E, int Etot,
    const float* __restrict__ EB, const unsigned* __restrict__ M, float* __restrict__ DEN) {
  const int e = blockIdx.x * 256 + threadIdx.x;
  if (e >= Etot) return;
  int d = (e < E) ? ei[E + e] : (e - E);
  if (H == 4) {
    float4 ev = *(const float4*)(EB + (size_t)e * 4);
    unsafeAtomicAdd(&DEN[d * 4 + 0], __expf(ev.x - decf(M[d * 4 + 0])));
    unsafeAtomicAdd(&DEN[d * 4 + 1], __expf(ev.y - decf(M[d * 4 + 1])));
    unsafeAtomicAdd(&DEN[d * 4 + 2], __expf(ev.z - decf(M[d * 4 + 2])));
    unsafeAtomicAdd(&DEN[d * 4 + 3], __expf(ev.w - decf(M[d * 4 + 3])));
  } else {
    unsafeAtomicAdd(&DEN[d], __expf(EB[e] - decf(M[d])));
  }
}

// ---- edge pass 3: out[dst] += h[src] * alpha  (128 lanes per edge) ----
template <int H>
__global__ __launch_bounds__(256) void epass3(const int* __restrict__ ei, int E, int Etot,
    const float* __restrict__ EB, const unsigned* __restrict__ M, const float* __restrict__ DEN,
    const float* __restrict__ Hin, float* __restrict__ Out) {
  const int idx = blockIdx.x * 2 + (threadIdx.x >> 7);
  if (idx >= Etot) return;
  const int f = threadIdx.x & 127;
  int s, d;
  if (idx < E) { s = ei[idx]; d = ei[E + idx]; } else { s = idx - E; d = s; }
  const int h = (H == 4) ? (f >> 5) : 0;
  float ev = EB[(size_t)idx * H + h];
  float m = decf(M[d * H + h]);
  float den = DEN[d * H + h];
  float alpha = __expf(ev - m) / (den + 1e-16f);
  float v = Hin[(size_t)s * 128 + f] * alpha;
  unsafeAtomicAdd(Out + (size_t)d * 128 + f, v);
}

// ---- bias add: Y[n,128] += B[128] ----
__global__ __launch_bounds__(256) void bias_add(float* __restrict__ Y,
                                                const float* __restrict__ B, int N) {
  const int i = blockIdx.x * 256 + threadIdx.x;
  if (i >= N * 32) return;
  float4 v = ((float4*)Y)[i];
  float4 b = ((const float4*)B)[i & 31];
  v.x += b.x; v.y += b.y; v.z += b.z; v.w += b.w;
  ((float4*)Y)[i] = v;
}

extern "C" void kernel_launch(void* const* d_in, const int* in_sizes, int n_in,
                              void* d_out, int out_size, void* d_ws, size_t ws_size,
                              hipStream_t stream) {
  const float* x    = (const float*)d_in[0];
  const int*   ei   = (const int*)d_in[1];
  const float* W1   = (const float*)d_in[2];
  const float* as1w = (const float*)d_in[3];
  const float* ad1w = (const float*)d_in[4];
  const float* b1   = (const float*)d_in[5];
  const float* W2   = (const float*)d_in[6];
  const float* as2w = (const float*)d_in[7];
  const float* ad2w = (const float*)d_in[8];
  const float* b2   = (const float*)d_in[9];

  const int N = in_sizes[0] / 128;
  const int E = in_sizes[1] / 2;
  const int Etot = E + N;

  char* ws = (char*)d_ws;
  size_t off = 0;
  auto alloc = [&](size_t bytes) -> void* {
    void* p = ws + off;
    off = (off + bytes + 255) & ~(size_t)255;
    return p;
  };
  float*    h12  = (float*)alloc((size_t)N * 128 * 4);  // h1, later reused as h2
  float*    out1 = (float*)alloc((size_t)N * 128 * 4);  // layer-1 output / layer-2 input
  float*    eb   = (float*)alloc((size_t)Etot * 4 * 4); // e values (reused in layer 2)
  float*    AS1  = (float*)alloc((size_t)N * 4 * 4);
  float*    AD1  = (float*)alloc((size_t)N * 4 * 4);
  unsigned* M1   = (unsigned*)alloc((size_t)N * 4 * 4);
  float*    DEN1 = (float*)alloc((size_t)N * 4 * 4);
  float*    AS2  = (float*)alloc((size_t)N * 4);
  float*    AD2  = (float*)alloc((size_t)N * 4);
  unsigned* M2   = (unsigned*)alloc((size_t)N * 4);
  float*    DEN2 = (float*)alloc((size_t)N * 4);

  hipMemsetAsync(out1, 0, (size_t)N * 128 * 4, stream);
  hipMemsetAsync(d_out, 0, (size_t)out_size * 4, stream);
  hipMemsetAsync(M1, 0, (size_t)N * 4 * 4, stream);   // encoded-min
  hipMemsetAsync(DEN1, 0, (size_t)N * 4 * 4, stream);
  hipMemsetAsync(M2, 0, (size_t)N * 4, stream);
  hipMemsetAsync(DEN2, 0, (size_t)N * 4, stream);

  const int eb1Blocks = (Etot + 255) / 256;
  const int eb3Blocks = (Etot + 1) / 2;

  // ---- layer 1 (H=4, C=32) ----
  gemm128<<<(N + 63) / 64, 256, 0, stream>>>(x, W1, h12, N);
  alphas_h4<<<(N * 4 + 7) / 8, 256, 0, stream>>>(h12, as1w, ad1w, AS1, AD1, N);
  epass1<4><<<eb1Blocks, 256, 0, stream>>>(ei, E, Etot, AS1, AD1, eb, M1);
  epass2<4><<<eb1Blocks, 256, 0, stream>>>(ei, E, Etot, eb, M1, DEN1);
  epass3<4><<<eb3Blocks, 256, 0, stream>>>(ei, E, Etot, eb, M1, DEN1, h12, out1);
  bias_add<<<(N * 32 + 255) / 256, 256, 0, stream>>>(out1, b1, N);

  // ---- layer 2 (H=1, C=128) ----
  gemm128<<<(N + 63) / 64, 256, 0, stream>>>(out1, W2, h12, N);
  alphas_h1<<<(N + 3) / 4, 256, 0, stream>>>(h12, as2w, ad2w, AS2, AD2, N);
  epass1<1><<<eb1Blocks, 256, 0, stream>>>(ei, E, Etot, AS2, AD2, eb, M2);
  epass2<1><<<eb1Blocks, 256, 0, stream>>>(ei, E, Etot, eb, M2, DEN2);
  epass3<1><<<eb3Blocks, 256, 0, stream>>>(ei, E, Etot, eb, M2, DEN2, h12, (float*)d_out);
  bias_add<<<(N * 32 + 255) / 256, 256, 0, stream>>>((float*)d_out, b2, N);
}

// Round 2
// 755.544 us; speedup vs baseline: 3.3216x; 3.3216x over previous
//
#include <hip/hip_runtime.h>
#include <cstdint>
#include <cstddef>

#define NEG_SLOPE 0.2f

__device__ __forceinline__ float lrelu(float v) { return v > 0.0f ? v : NEG_SLOPE * v; }

// ---- GEMM: Y[N,128] = X[N,128] @ W[128,128], fp32 ----
__global__ __launch_bounds__(256) void gemm128(const float* __restrict__ X,
                                               const float* __restrict__ W,
                                               float* __restrict__ Y, int N) {
  __shared__ float xs[64 * 132];
  const int tid = threadIdx.x;
  const int rowBase = blockIdx.x * 64;
  const int rowsHere = min(64, N - rowBase);
  for (int i = tid; i < 64 * 32; i += 256) {
    int r = i >> 5, c4 = i & 31;
    float4 v = make_float4(0.f, 0.f, 0.f, 0.f);
    if (r < rowsHere) v = *(const float4*)(X + (size_t)(rowBase + r) * 128 + c4 * 4);
    *(float4*)(xs + r * 132 + c4 * 4) = v;
  }
  __syncthreads();
  const int j0 = (tid & 31) * 4;
  const int r0 = (tid >> 5) * 8;
  float4 acc[8];
#pragma unroll
  for (int r = 0; r < 8; ++r) acc[r] = make_float4(0.f, 0.f, 0.f, 0.f);
  for (int k0 = 0; k0 < 128; k0 += 4) {
    float4 w0 = *(const float4*)(W + (size_t)(k0 + 0) * 128 + j0);
    float4 w1 = *(const float4*)(W + (size_t)(k0 + 1) * 128 + j0);
    float4 w2 = *(const float4*)(W + (size_t)(k0 + 2) * 128 + j0);
    float4 w3 = *(const float4*)(W + (size_t)(k0 + 3) * 128 + j0);
#pragma unroll
    for (int r = 0; r < 8; ++r) {
      float4 xv = *(const float4*)(xs + (r0 + r) * 132 + k0);
      acc[r].x += xv.x * w0.x + xv.y * w1.x + xv.z * w2.x + xv.w * w3.x;
      acc[r].y += xv.x * w0.y + xv.y * w1.y + xv.z * w2.y + xv.w * w3.y;
      acc[r].z += xv.x * w0.z + xv.y * w1.z + xv.z * w2.z + xv.w * w3.z;
      acc[r].w += xv.x * w0.w + xv.y * w1.w + xv.z * w2.w + xv.w * w3.w;
    }
  }
#pragma unroll
  for (int r = 0; r < 8; ++r) {
    int row = r0 + r;
    if (row < rowsHere) *(float4*)(Y + (size_t)(rowBase + row) * 128 + j0) = acc[r];
  }
}

// ---- alpha_src/alpha_dst for H=4, C=32 ----
__global__ __launch_bounds__(256) void alphas_h4(const float* __restrict__ Hm,
    const float* __restrict__ Asrc, const float* __restrict__ Adst,
    float* __restrict__ AS, float* __restrict__ AD, int N) {
  const int tid = threadIdx.x;
  const int g = blockIdx.x * 8 + (tid >> 5);
  if (g >= N * 4) return;
  const int lane = tid & 31;
  const int h = g & 3;
  float v = Hm[(size_t)g * 32 + lane];
  float as = v * Asrc[h * 32 + lane];
  float ad = v * Adst[h * 32 + lane];
#pragma unroll
  for (int o = 16; o >= 1; o >>= 1) {
    as += __shfl_xor(as, o, 64);
    ad += __shfl_xor(ad, o, 64);
  }
  if (lane == 0) { AS[g] = as; AD[g] = ad; }
}

// ---- alpha_src/alpha_dst for H=1, C=128 ----
__global__ __launch_bounds__(256) void alphas_h1(const float* __restrict__ Hm,
    const float* __restrict__ Asrc, const float* __restrict__ Adst,
    float* __restrict__ AS, float* __restrict__ AD, int N) {
  const int tid = threadIdx.x;
  const int n = blockIdx.x * 4 + (tid >> 6);
  if (n >= N) return;
  const int lane = tid & 63;
  float v0 = Hm[(size_t)n * 128 + lane];
  float v1 = Hm[(size_t)n * 128 + 64 + lane];
  float as = v0 * Asrc[lane] + v1 * Asrc[64 + lane];
  float ad = v0 * Adst[lane] + v1 * Adst[64 + lane];
#pragma unroll
  for (int o = 32; o >= 1; o >>= 1) {
    as += __shfl_xor(as, o, 64);
    ad += __shfl_xor(ad, o, 64);
  }
  if (lane == 0) { AS[n] = as; AD[n] = ad; }
}

// ================= CSR build =================
__global__ __launch_bounds__(256) void csr_count(const int* __restrict__ ei, int E, int Etot,
                                                 int* __restrict__ cnt) {
  int e = blockIdx.x * 256 + threadIdx.x;
  if (e >= Etot) return;
  int d = (e < E) ? ei[E + e] : (e - E);
  atomicAdd(&cnt[d], 1);
}

__global__ __launch_bounds__(256) void scan_blocks(const int* __restrict__ cnt,
                                                   int* __restrict__ rowStart,
                                                   int* __restrict__ blockSums, int N) {
  __shared__ int sh[256];
  const int tid = threadIdx.x;
  const int i = blockIdx.x * 256 + tid;
  int v = (i < N) ? cnt[i] : 0;
  sh[tid] = v;
  __syncthreads();
  for (int o = 1; o < 256; o <<= 1) {
    int t = (tid >= o) ? sh[tid - o] : 0;
    __syncthreads();
    sh[tid] += t;
    __syncthreads();
  }
  if (i < N) rowStart[i] = sh[tid] - v;  // exclusive within block
  if (tid == 255) blockSums[blockIdx.x] = sh[255];
}

__global__ __launch_bounds__(256) void scan_sums(int* __restrict__ bs, int nb) {
  __shared__ int sh[256];
  __shared__ int carryS;
  const int tid = threadIdx.x;
  if (tid == 0) carryS = 0;
  __syncthreads();
  for (int c = 0; c < nb; c += 256) {
    int i = c + tid;
    int v = (i < nb) ? bs[i] : 0;
    sh[tid] = v;
    __syncthreads();
    for (int o = 1; o < 256; o <<= 1) {
      int t = (tid >= o) ? sh[tid - o] : 0;
      __syncthreads();
      sh[tid] += t;
      __syncthreads();
    }
    int carry = carryS;
    if (i < nb) bs[i] = carry + sh[tid] - v;
    int total = sh[255];
    __syncthreads();
    if (tid == 0) carryS = carry + total;
    __syncthreads();
  }
}

__global__ __launch_bounds__(256) void add_offsets(int* __restrict__ rowStart,
                                                   const int* __restrict__ bs,
                                                   int* __restrict__ cursor, int N, int Etot) {
  int i = blockIdx.x * 256 + threadIdx.x;
  if (i == 0) rowStart[N] = Etot;
  if (i >= N) return;
  int r = rowStart[i] + bs[i >> 8];
  rowStart[i] = r;
  cursor[i] = r;
}

__global__ __launch_bounds__(256) void csr_scatter(const int* __restrict__ ei, int E, int Etot,
                                                   int* __restrict__ cursor,
                                                   int* __restrict__ srcS) {
  int e = blockIdx.x * 256 + threadIdx.x;
  if (e >= Etot) return;
  int s, d;
  if (e < E) { s = ei[e]; d = ei[E + e]; } else { s = e - E; d = s; }
  int pos = atomicAdd(&cursor[d], 1);
  srcS[pos] = s;
}

// ========== fused per-node softmax + aggregate (+bias), one wave per node ==========
template <int H>
__global__ __launch_bounds__(256) void gat_node(
    const int* __restrict__ rowStart, const int* __restrict__ srcS,
    const float* __restrict__ AS, const float* __restrict__ AD,
    const float* __restrict__ Hin, const float* __restrict__ B,
    float* __restrict__ Out, int N) {
  const int n = blockIdx.x * 4 + (threadIdx.x >> 6);
  if (n >= N) return;
  const int lane = threadIdx.x & 63;
  const int beg = rowStart[n];
  const int end = rowStart[n + 1];

  float4 adv = make_float4(0.f, 0.f, 0.f, 0.f);
  if (H == 4) adv = *(const float4*)(AD + (size_t)n * 4);
  else adv.x = AD[n];

  // ---- pass 1: per-head max over edges ----
  float4 m = make_float4(-INFINITY, -INFINITY, -INFINITY, -INFINITY);
  for (int base = beg; base < end; base += 64) {
    int i = base + lane;
    if (i < end) {
      int s = srcS[i];
      if (H == 4) {
        float4 as = *(const float4*)(AS + (size_t)s * 4);
        m.x = fmaxf(m.x, lrelu(as.x + adv.x));
        m.y = fmaxf(m.y, lrelu(as.y + adv.y));
        m.z = fmaxf(m.z, lrelu(as.z + adv.z));
        m.w = fmaxf(m.w, lrelu(as.w + adv.w));
      } else {
        m.x = fmaxf(m.x, lrelu(AS[s] + adv.x));
      }
    }
  }
#pragma unroll
  for (int o = 32; o >= 1; o >>= 1) {
    m.x = fmaxf(m.x, __shfl_xor(m.x, o, 64));
    if (H == 4) {
      m.y = fmaxf(m.y, __shfl_xor(m.y, o, 64));
      m.z = fmaxf(m.z, __shfl_xor(m.z, o, 64));
      m.w = fmaxf(m.w, __shfl_xor(m.w, o, 64));
    }
  }

  // ---- pass 2: denom ----
  float4 den = make_float4(0.f, 0.f, 0.f, 0.f);
  for (int base = beg; base < end; base += 64) {
    int i = base + lane;
    if (i < end) {
      int s = srcS[i];
      if (H == 4) {
        float4 as = *(const float4*)(AS + (size_t)s * 4);
        den.x += __expf(lrelu(as.x + adv.x) - m.x);
        den.y += __expf(lrelu(as.y + adv.y) - m.y);
        den.z += __expf(lrelu(as.z + adv.z) - m.z);
        den.w += __expf(lrelu(as.w + adv.w) - m.w);
      } else {
        den.x += __expf(lrelu(AS[s] + adv.x) - m.x);
      }
    }
  }
#pragma unroll
  for (int o = 32; o >= 1; o >>= 1) {
    den.x += __shfl_xor(den.x, o, 64);
    if (H == 4) {
      den.y += __shfl_xor(den.y, o, 64);
      den.z += __shfl_xor(den.z, o, 64);
      den.w += __shfl_xor(den.w, o, 64);
    }
  }
  float4 inv;
  inv.x = 1.0f / (den.x + 1e-16f);
  if (H == 4) {
    inv.y = 1.0f / (den.y + 1e-16f);
    inv.z = 1.0f / (den.z + 1e-16f);
    inv.w = 1.0f / (den.w + 1e-16f);
  }

  // ---- pass 3: weighted gather-accumulate ----
  // lane owns features f0 = 2*lane, 2*lane+1 (same head: head = lane>>4 for H=4)
  const int f0 = lane * 2;
  const int myh = (H == 4) ? (lane >> 4) : 0;
  float accx = 0.f, accy = 0.f;
  for (int base = beg; base < end; base += 64) {
    int i = base + lane;
    int s = 0;
    float4 a4 = make_float4(0.f, 0.f, 0.f, 0.f);
    if (i < end) {
      s = srcS[i];
      if (H == 4) {
        float4 as = *(const float4*)(AS + (size_t)s * 4);
        a4.x = __expf(lrelu(as.x + adv.x) - m.x) * inv.x;
        a4.y = __expf(lrelu(as.y + adv.y) - m.y) * inv.y;
        a4.z = __expf(lrelu(as.z + adv.z) - m.z) * inv.z;
        a4.w = __expf(lrelu(as.w + adv.w) - m.w) * inv.w;
      } else {
        a4.x = __expf(lrelu(AS[s] + adv.x) - m.x) * inv.x;
      }
    }
    int cnt = min(64, end - base);
    for (int j = 0; j < cnt; ++j) {
      int sj = __shfl(s, j, 64);
      float aj;
      if (H == 4) {
        float ax = __shfl(a4.x, j, 64);
        float ay = __shfl(a4.y, j, 64);
        float az = __shfl(a4.z, j, 64);
        float aw = __shfl(a4.w, j, 64);
        aj = (myh == 0) ? ax : (myh == 1) ? ay : (myh == 2) ? az : aw;
      } else {
        aj = __shfl(a4.x, j, 64);
      }
      float2 hv = *(const float2*)(Hin + (size_t)sj * 128 + f0);
      accx += hv.x * aj;
      accy += hv.y * aj;
    }
  }
  float2 outv;
  outv.x = accx + B[f0];
  outv.y = accy + B[f0 + 1];
  *(float2*)(Out + (size_t)n * 128 + f0) = outv;
}

extern "C" void kernel_launch(void* const* d_in, const int* in_sizes, int n_in,
                              void* d_out, int out_size, void* d_ws, size_t ws_size,
                              hipStream_t stream) {
  const float* x    = (const float*)d_in[0];
  const int*   ei   = (const int*)d_in[1];
  const float* W1   = (const float*)d_in[2];
  const float* as1w = (const float*)d_in[3];
  const float* ad1w = (const float*)d_in[4];
  const float* b1   = (const float*)d_in[5];
  const float* W2   = (const float*)d_in[6];
  const float* as2w = (const float*)d_in[7];
  const float* ad2w = (const float*)d_in[8];
  const float* b2   = (const float*)d_in[9];

  const int N = in_sizes[0] / 128;
  const int E = in_sizes[1] / 2;
  const int Etot = E + N;
  const int nb = (N + 255) / 256;

  char* ws = (char*)d_ws;
  size_t off = 0;
  auto alloc = [&](size_t bytes) -> void* {
    void* p = ws + off;
    off = (off + bytes + 255) & ~(size_t)255;
    return p;
  };
  float* h12  = (float*)alloc((size_t)N * 128 * 4);
  float* out1 = (float*)alloc((size_t)N * 128 * 4);
  float* AS1  = (float*)alloc((size_t)N * 4 * 4);
  float* AD1  = (float*)alloc((size_t)N * 4 * 4);
  float* AS2  = (float*)alloc((size_t)N * 4);
  float* AD2  = (float*)alloc((size_t)N * 4);
  int*   cnt      = (int*)alloc((size_t)N * 4);
  int*   rowStart = (int*)alloc((size_t)(N + 1) * 4);
  int*   cursor   = (int*)alloc((size_t)N * 4);
  int*   blockSums= (int*)alloc((size_t)nb * 4);
  int*   srcS     = (int*)alloc((size_t)Etot * 4);

  // ---- CSR build (once, used by both layers) ----
  hipMemsetAsync(cnt, 0, (size_t)N * 4, stream);
  const int ebBlocks = (Etot + 255) / 256;
  csr_count<<<ebBlocks, 256, 0, stream>>>(ei, E, Etot, cnt);
  scan_blocks<<<nb, 256, 0, stream>>>(cnt, rowStart, blockSums, N);
  scan_sums<<<1, 256, 0, stream>>>(blockSums, nb);
  add_offsets<<<nb, 256, 0, stream>>>(rowStart, blockSums, cursor, N, Etot);
  csr_scatter<<<ebBlocks, 256, 0, stream>>>(ei, E, Etot, cursor, srcS);

  const int nodeBlocks = (N + 3) / 4;

  // ---- layer 1 (H=4, C=32) ----
  gemm128<<<(N + 63) / 64, 256, 0, stream>>>(x, W1, h12, N);
  alphas_h4<<<(N * 4 + 7) / 8, 256, 0, stream>>>(h12, as1w, ad1w, AS1, AD1, N);
  gat_node<4><<<nodeBlocks, 256, 0, stream>>>(rowStart, srcS, AS1, AD1, h12, b1, out1, N);

  // ---- layer 2 (H=1, C=128) ----
  gemm128<<<(N + 63) / 64, 256, 0, stream>>>(out1, W2, h12, N);
  alphas_h1<<<(N + 3) / 4, 256, 0, stream>>>(h12, as2w, ad2w, AS2, AD2, N);
  gat_node<1><<<nodeBlocks, 256, 0, stream>>>(rowStart, srcS, AS2, AD2, h12, b2, (float*)d_out, N);
}

// Round 3
// 570.893 us; speedup vs baseline: 4.3960x; 1.3234x over previous
//
#include <hip/hip_runtime.h>
#include <cstdint>
#include <cstddef>

#define NEG_SLOPE 0.2f

__device__ __forceinline__ float lrelu(float v) { return v > 0.0f ? v : NEG_SLOPE * v; }

__device__ __forceinline__ unsigned short f2bf(float f) {
  unsigned u = __float_as_uint(f);
  unsigned r = (u + 0x7fff + ((u >> 16) & 1)) >> 16;  // RNE
  return (unsigned short)r;
}

// ---- GEMM: Ybf[N,128](bf16) = X[N,128] @ W[128,128]; fused alpha_src/dst ----
// 64 rows/block, 256 threads, 8 rows x 4 cols per thread.
template <int H>
__global__ __launch_bounds__(256) void gemm128_fused(
    const float* __restrict__ X, const float* __restrict__ W,
    const float* __restrict__ AsrcW, const float* __restrict__ AdstW,
    unsigned short* __restrict__ Ybf, float* __restrict__ AS, float* __restrict__ AD,
    int N) {
  __shared__ float xs[64 * 132];
  const int tid = threadIdx.x;
  const int rowBase = blockIdx.x * 64;
  const int rowsHere = min(64, N - rowBase);
  for (int i = tid; i < 64 * 32; i += 256) {
    int r = i >> 5, c4 = i & 31;
    float4 v = make_float4(0.f, 0.f, 0.f, 0.f);
    if (r < rowsHere) v = *(const float4*)(X + (size_t)(rowBase + r) * 128 + c4 * 4);
    *(float4*)(xs + r * 132 + c4 * 4) = v;
  }
  __syncthreads();
  const int j0 = (tid & 31) * 4;
  const int r0 = (tid >> 5) * 8;
  float4 acc[8];
#pragma unroll
  for (int r = 0; r < 8; ++r) acc[r] = make_float4(0.f, 0.f, 0.f, 0.f);
  for (int k0 = 0; k0 < 128; k0 += 4) {
    float4 w0 = *(const float4*)(W + (size_t)(k0 + 0) * 128 + j0);
    float4 w1 = *(const float4*)(W + (size_t)(k0 + 1) * 128 + j0);
    float4 w2 = *(const float4*)(W + (size_t)(k0 + 2) * 128 + j0);
    float4 w3 = *(const float4*)(W + (size_t)(k0 + 3) * 128 + j0);
#pragma unroll
    for (int r = 0; r < 8; ++r) {
      float4 xv = *(const float4*)(xs + (r0 + r) * 132 + k0);
      acc[r].x += xv.x * w0.x + xv.y * w1.x + xv.z * w2.x + xv.w * w3.x;
      acc[r].y += xv.x * w0.y + xv.y * w1.y + xv.z * w2.y + xv.w * w3.y;
      acc[r].z += xv.x * w0.z + xv.y * w1.z + xv.z * w2.z + xv.w * w3.z;
      acc[r].w += xv.x * w0.w + xv.y * w1.w + xv.z * w2.w + xv.w * w3.w;
    }
  }
  // epilogue: bf16 store + fused alpha reductions (from fp32 acc)
  const float4 asw = *(const float4*)(AsrcW + j0);
  const float4 adw = *(const float4*)(AdstW + j0);
  const int Wd = (H == 4) ? 8 : 32;  // threads per (row, head) reduction
#pragma unroll
  for (int r = 0; r < 8; ++r) {
    int row = r0 + r;
    bool valid = row < rowsHere;
    if (valid) {
      ushort4 bv;
      bv.x = f2bf(acc[r].x); bv.y = f2bf(acc[r].y);
      bv.z = f2bf(acc[r].z); bv.w = f2bf(acc[r].w);
      *(ushort4*)(Ybf + (size_t)(rowBase + row) * 128 + j0) = bv;
    }
    float pas = acc[r].x * asw.x + acc[r].y * asw.y + acc[r].z * asw.z + acc[r].w * asw.w;
    float pad = acc[r].x * adw.x + acc[r].y * adw.y + acc[r].z * adw.z + acc[r].w * adw.w;
#pragma unroll
    for (int o = Wd / 2; o >= 1; o >>= 1) {
      pas += __shfl_xor(pas, o, Wd);
      pad += __shfl_xor(pad, o, Wd);
    }
    if ((tid & (Wd - 1)) == 0 && valid) {
      int idx = (H == 4) ? ((rowBase + row) * 4 + (j0 >> 5)) : (rowBase + row);
      AS[idx] = pas;
      AD[idx] = pad;
    }
  }
}

// ================= CSR build =================
__global__ __launch_bounds__(256) void csr_count(const int* __restrict__ ei, int E, int Etot,
                                                 int* __restrict__ cnt) {
  int e = blockIdx.x * 256 + threadIdx.x;
  if (e >= Etot) return;
  int d = (e < E) ? ei[E + e] : (e - E);
  atomicAdd(&cnt[d], 1);
}

__global__ __launch_bounds__(256) void scan_blocks(const int* __restrict__ cnt,
                                                   int* __restrict__ rowStart,
                                                   int* __restrict__ blockSums, int N) {
  __shared__ int sh[256];
  const int tid = threadIdx.x;
  const int i = blockIdx.x * 256 + tid;
  int v = (i < N) ? cnt[i] : 0;
  sh[tid] = v;
  __syncthreads();
  for (int o = 1; o < 256; o <<= 1) {
    int t = (tid >= o) ? sh[tid - o] : 0;
    __syncthreads();
    sh[tid] += t;
    __syncthreads();
  }
  if (i < N) rowStart[i] = sh[tid] - v;
  if (tid == 255) blockSums[blockIdx.x] = sh[255];
}

__global__ __launch_bounds__(256) void scan_sums(int* __restrict__ bs, int nb) {
  __shared__ int sh[256];
  __shared__ int carryS;
  const int tid = threadIdx.x;
  if (tid == 0) carryS = 0;
  __syncthreads();
  for (int c = 0; c < nb; c += 256) {
    int i = c + tid;
    int v = (i < nb) ? bs[i] : 0;
    sh[tid] = v;
    __syncthreads();
    for (int o = 1; o < 256; o <<= 1) {
      int t = (tid >= o) ? sh[tid - o] : 0;
      __syncthreads();
      sh[tid] += t;
      __syncthreads();
    }
    int carry = carryS;
    if (i < nb) bs[i] = carry + sh[tid] - v;
    int total = sh[255];
    __syncthreads();
    if (tid == 0) carryS = carry + total;
    __syncthreads();
  }
}

__global__ __launch_bounds__(256) void add_offsets(int* __restrict__ rowStart,
                                                   const int* __restrict__ bs,
                                                   int* __restrict__ cursor, int N, int Etot) {
  int i = blockIdx.x * 256 + threadIdx.x;
  if (i == 0) rowStart[N] = Etot;
  if (i >= N) return;
  int r = rowStart[i] + bs[i >> 8];
  rowStart[i] = r;
  cursor[i] = r;
}

__global__ __launch_bounds__(256) void csr_scatter(const int* __restrict__ ei, int E, int Etot,
                                                   int* __restrict__ cursor,
                                                   int* __restrict__ srcS) {
  int e = blockIdx.x * 256 + threadIdx.x;
  if (e >= Etot) return;
  int s, d;
  if (e < E) { s = ei[e]; d = ei[E + e]; } else { s = e - E; d = s; }
  int pos = atomicAdd(&cursor[d], 1);
  srcS[pos] = s;
}

// ==== fused per-node online-softmax + bf16 gather-aggregate, 16 lanes/node ====
template <int H>
__global__ __launch_bounds__(256) void gat_node(
    const int* __restrict__ rowStart, const int* __restrict__ srcS,
    const float* __restrict__ AS, const float* __restrict__ AD,
    const unsigned short* __restrict__ Hbf, const float* __restrict__ B,
    float* __restrict__ Out, int N) {
  const int n = blockIdx.x * 16 + (threadIdx.x >> 4);
  if (n >= N) return;
  const int l = threadIdx.x & 15;
  const int beg = rowStart[n];
  const int end = rowStart[n + 1];
  const int f0 = l * 8;
  const int myh = (H == 4) ? (l >> 2) : 0;

  float4 adv = make_float4(0.f, 0.f, 0.f, 0.f);
  if (H == 4) adv = *(const float4*)(AD + (size_t)n * 4);
  else adv.x = AD[n];

  float4 m = make_float4(-INFINITY, -INFINITY, -INFINITY, -INFINITY);
  float4 den = make_float4(0.f, 0.f, 0.f, 0.f);
  float acc[8];
#pragma unroll
  for (int k = 0; k < 8; ++k) acc[k] = 0.f;

  for (int base = beg; base < end; base += 16) {
    const int i = base + l;
    int s = 0;
    float4 e = make_float4(-INFINITY, -INFINITY, -INFINITY, -INFINITY);
    if (i < end) {
      s = srcS[i];
      if (H == 4) {
        float4 as = *(const float4*)(AS + (size_t)s * 4);
        e.x = lrelu(as.x + adv.x);
        e.y = lrelu(as.y + adv.y);
        e.z = lrelu(as.z + adv.z);
        e.w = lrelu(as.w + adv.w);
      } else {
        e.x = lrelu(AS[s] + adv.x);
      }
    }
    // chunk max across 16 lanes
    float4 cm = e;
#pragma unroll
    for (int o = 8; o >= 1; o >>= 1) {
      cm.x = fmaxf(cm.x, __shfl_xor(cm.x, o, 16));
      if (H == 4) {
        cm.y = fmaxf(cm.y, __shfl_xor(cm.y, o, 16));
        cm.z = fmaxf(cm.z, __shfl_xor(cm.z, o, 16));
        cm.w = fmaxf(cm.w, __shfl_xor(cm.w, o, 16));
      }
    }
    float4 mN, rs, p;
    mN.x = fmaxf(m.x, cm.x);
    rs.x = __expf(m.x - mN.x);
    p.x = __expf(e.x - mN.x);
    if (H == 4) {
      mN.y = fmaxf(m.y, cm.y); rs.y = __expf(m.y - mN.y); p.y = __expf(e.y - mN.y);
      mN.z = fmaxf(m.z, cm.z); rs.z = __expf(m.z - mN.z); p.z = __expf(e.z - mN.z);
      mN.w = fmaxf(m.w, cm.w); rs.w = __expf(m.w - mN.w); p.w = __expf(e.w - mN.w);
    }
    m = mN;
    // chunk sum of p
    float4 cs = p;
#pragma unroll
    for (int o = 8; o >= 1; o >>= 1) {
      cs.x += __shfl_xor(cs.x, o, 16);
      if (H == 4) {
        cs.y += __shfl_xor(cs.y, o, 16);
        cs.z += __shfl_xor(cs.z, o, 16);
        cs.w += __shfl_xor(cs.w, o, 16);
      }
    }
    den.x = den.x * rs.x + cs.x;
    float accScale = rs.x;
    if (H == 4) {
      den.y = den.y * rs.y + cs.y;
      den.z = den.z * rs.z + cs.z;
      den.w = den.w * rs.w + cs.w;
      accScale = (myh == 0) ? rs.x : (myh == 1) ? rs.y : (myh == 2) ? rs.z : rs.w;
    }
#pragma unroll
    for (int k = 0; k < 8; ++k) acc[k] *= accScale;

    const int cnt = min(16, end - base);
    for (int j = 0; j < cnt; ++j) {
      const int sj = __shfl(s, j, 16);
      float aj;
      if (H == 4) {
        float ax = __shfl(p.x, j, 16);
        float ay = __shfl(p.y, j, 16);
        float az = __shfl(p.z, j, 16);
        float aw = __shfl(p.w, j, 16);
        aj = (myh == 0) ? ax : (myh == 1) ? ay : (myh == 2) ? az : aw;
      } else {
        aj = __shfl(p.x, j, 16);
      }
      const uint4 hv = *(const uint4*)(Hbf + (size_t)sj * 128 + f0);
      acc[0] += __uint_as_float(hv.x << 16) * aj;
      acc[1] += __uint_as_float(hv.x & 0xffff0000u) * aj;
      acc[2] += __uint_as_float(hv.y << 16) * aj;
      acc[3] += __uint_as_float(hv.y & 0xffff0000u) * aj;
      acc[4] += __uint_as_float(hv.z << 16) * aj;
      acc[5] += __uint_as_float(hv.z & 0xffff0000u) * aj;
      acc[6] += __uint_as_float(hv.w << 16) * aj;
      acc[7] += __uint_as_float(hv.w & 0xffff0000u) * aj;
    }
  }
  float denf = den.x;
  if (H == 4) denf = (myh == 0) ? den.x : (myh == 1) ? den.y : (myh == 2) ? den.z : den.w;
  const float inv = 1.0f / (denf + 1e-16f);
  float4 o0, o1;
  o0.x = acc[0] * inv + B[f0 + 0];
  o0.y = acc[1] * inv + B[f0 + 1];
  o0.z = acc[2] * inv + B[f0 + 2];
  o0.w = acc[3] * inv + B[f0 + 3];
  o1.x = acc[4] * inv + B[f0 + 4];
  o1.y = acc[5] * inv + B[f0 + 5];
  o1.z = acc[6] * inv + B[f0 + 6];
  o1.w = acc[7] * inv + B[f0 + 7];
  *(float4*)(Out + (size_t)n * 128 + f0) = o0;
  *(float4*)(Out + (size_t)n * 128 + f0 + 4) = o1;
}

extern "C" void kernel_launch(void* const* d_in, const int* in_sizes, int n_in,
                              void* d_out, int out_size, void* d_ws, size_t ws_size,
                              hipStream_t stream) {
  const float* x    = (const float*)d_in[0];
  const int*   ei   = (const int*)d_in[1];
  const float* W1   = (const float*)d_in[2];
  const float* as1w = (const float*)d_in[3];
  const float* ad1w = (const float*)d_in[4];
  const float* b1   = (const float*)d_in[5];
  const float* W2   = (const float*)d_in[6];
  const float* as2w = (const float*)d_in[7];
  const float* ad2w = (const float*)d_in[8];
  const float* b2   = (const float*)d_in[9];

  const int N = in_sizes[0] / 128;
  const int E = in_sizes[1] / 2;
  const int Etot = E + N;
  const int nb = (N + 255) / 256;

  char* ws = (char*)d_ws;
  size_t off = 0;
  auto alloc = [&](size_t bytes) -> void* {
    void* p = ws + off;
    off = (off + bytes + 255) & ~(size_t)255;
    return p;
  };
  unsigned short* Hbf  = (unsigned short*)alloc((size_t)N * 128 * 2);  // h (bf16), reused layer 2
  float* out1 = (float*)alloc((size_t)N * 128 * 4);
  float* AS1  = (float*)alloc((size_t)N * 4 * 4);
  float* AD1  = (float*)alloc((size_t)N * 4 * 4);
  float* AS2  = (float*)alloc((size_t)N * 4);
  float* AD2  = (float*)alloc((size_t)N * 4);
  int*   cnt      = (int*)alloc((size_t)N * 4);
  int*   rowStart = (int*)alloc((size_t)(N + 1) * 4);
  int*   cursor   = (int*)alloc((size_t)N * 4);
  int*   blockSums= (int*)alloc((size_t)nb * 4);
  int*   srcS     = (int*)alloc((size_t)Etot * 4);

  // ---- CSR build (once, shared by both layers) ----
  hipMemsetAsync(cnt, 0, (size_t)N * 4, stream);
  const int ebBlocks = (Etot + 255) / 256;
  csr_count<<<ebBlocks, 256, 0, stream>>>(ei, E, Etot, cnt);
  scan_blocks<<<nb, 256, 0, stream>>>(cnt, rowStart, blockSums, N);
  scan_sums<<<1, 256, 0, stream>>>(blockSums, nb);
  add_offsets<<<nb, 256, 0, stream>>>(rowStart, blockSums, cursor, N, Etot);
  csr_scatter<<<ebBlocks, 256, 0, stream>>>(ei, E, Etot, cursor, srcS);

  const int gemmBlocks = (N + 63) / 64;
  const int nodeBlocks = (N + 15) / 16;

  // ---- layer 1 (H=4, C=32) ----
  gemm128_fused<4><<<gemmBlocks, 256, 0, stream>>>(x, W1, as1w, ad1w, Hbf, AS1, AD1, N);
  gat_node<4><<<nodeBlocks, 256, 0, stream>>>(rowStart, srcS, AS1, AD1, Hbf, b1, out1, N);

  // ---- layer 2 (H=1, C=128) ----
  gemm128_fused<1><<<gemmBlocks, 256, 0, stream>>>(out1, W2, as2w, ad2w, Hbf, AS2, AD2, N);
  gat_node<1><<<nodeBlocks, 256, 0, stream>>>(rowStart, srcS, AS2, AD2, Hbf, b2, (float*)d_out, N);
}

// Round 4
// 521.769 us; speedup vs baseline: 4.8098x; 1.0941x over previous
//
#include <hip/hip_runtime.h>
#include <cstdint>
#include <cstddef>

#define NEG_SLOPE 0.2f

__device__ __forceinline__ float lrelu(float v) { return v > 0.0f ? v : NEG_SLOPE * v; }

__device__ __forceinline__ unsigned short f2bf(float f) {
  unsigned u = __float_as_uint(f);
  unsigned r = (u + 0x7fff + ((u >> 16) & 1)) >> 16;  // RNE
  return (unsigned short)r;
}

// ---- GEMM: Ybf[N,128](bf16) = X[N,128] @ W[128,128]; fused alpha_src/dst ----
template <int H>
__global__ __launch_bounds__(256) void gemm128_fused(
    const float* __restrict__ X, const float* __restrict__ W,
    const float* __restrict__ AsrcW, const float* __restrict__ AdstW,
    unsigned short* __restrict__ Ybf, float* __restrict__ AS, float* __restrict__ AD,
    int N) {
  __shared__ float xs[64 * 132];
  const int tid = threadIdx.x;
  const int rowBase = blockIdx.x * 64;
  const int rowsHere = min(64, N - rowBase);
  for (int i = tid; i < 64 * 32; i += 256) {
    int r = i >> 5, c4 = i & 31;
    float4 v = make_float4(0.f, 0.f, 0.f, 0.f);
    if (r < rowsHere) v = *(const float4*)(X + (size_t)(rowBase + r) * 128 + c4 * 4);
    *(float4*)(xs + r * 132 + c4 * 4) = v;
  }
  __syncthreads();
  const int j0 = (tid & 31) * 4;
  const int r0 = (tid >> 5) * 8;
  float4 acc[8];
#pragma unroll
  for (int r = 0; r < 8; ++r) acc[r] = make_float4(0.f, 0.f, 0.f, 0.f);
  for (int k0 = 0; k0 < 128; k0 += 4) {
    float4 w0 = *(const float4*)(W + (size_t)(k0 + 0) * 128 + j0);
    float4 w1 = *(const float4*)(W + (size_t)(k0 + 1) * 128 + j0);
    float4 w2 = *(const float4*)(W + (size_t)(k0 + 2) * 128 + j0);
    float4 w3 = *(const float4*)(W + (size_t)(k0 + 3) * 128 + j0);
#pragma unroll
    for (int r = 0; r < 8; ++r) {
      float4 xv = *(const float4*)(xs + (r0 + r) * 132 + k0);
      acc[r].x += xv.x * w0.x + xv.y * w1.x + xv.z * w2.x + xv.w * w3.x;
      acc[r].y += xv.x * w0.y + xv.y * w1.y + xv.z * w2.y + xv.w * w3.y;
      acc[r].z += xv.x * w0.z + xv.y * w1.z + xv.z * w2.z + xv.w * w3.z;
      acc[r].w += xv.x * w0.w + xv.y * w1.w + xv.z * w2.w + xv.w * w3.w;
    }
  }
  const float4 asw = *(const float4*)(AsrcW + j0);
  const float4 adw = *(const float4*)(AdstW + j0);
  const int Wd = (H == 4) ? 8 : 32;
#pragma unroll
  for (int r = 0; r < 8; ++r) {
    int row = r0 + r;
    bool valid = row < rowsHere;
    if (valid) {
      ushort4 bv;
      bv.x = f2bf(acc[r].x); bv.y = f2bf(acc[r].y);
      bv.z = f2bf(acc[r].z); bv.w = f2bf(acc[r].w);
      *(ushort4*)(Ybf + (size_t)(rowBase + row) * 128 + j0) = bv;
    }
    float pas = acc[r].x * asw.x + acc[r].y * asw.y + acc[r].z * asw.z + acc[r].w * asw.w;
    float pad = acc[r].x * adw.x + acc[r].y * adw.y + acc[r].z * adw.z + acc[r].w * adw.w;
#pragma unroll
    for (int o = Wd / 2; o >= 1; o >>= 1) {
      pas += __shfl_xor(pas, o, Wd);
      pad += __shfl_xor(pad, o, Wd);
    }
    if ((tid & (Wd - 1)) == 0 && valid) {
      int idx = (H == 4) ? ((rowBase + row) * 4 + (j0 >> 5)) : (rowBase + row);
      AS[idx] = pas;
      AD[idx] = pad;
    }
  }
}

// ================= CSR build =================
__global__ __launch_bounds__(256) void csr_count(const int* __restrict__ ei, int E, int Etot,
                                                 int* __restrict__ cnt) {
  int e = blockIdx.x * 256 + threadIdx.x;
  if (e >= Etot) return;
  int d = (e < E) ? ei[E + e] : (e - E);
  atomicAdd(&cnt[d], 1);
}

__global__ __launch_bounds__(256) void scan_blocks(const int* __restrict__ cnt,
                                                   int* __restrict__ rowStart,
                                                   int* __restrict__ blockSums, int N) {
  __shared__ int sh[256];
  const int tid = threadIdx.x;
  const int i = blockIdx.x * 256 + tid;
  int v = (i < N) ? cnt[i] : 0;
  sh[tid] = v;
  __syncthreads();
  for (int o = 1; o < 256; o <<= 1) {
    int t = (tid >= o) ? sh[tid - o] : 0;
    __syncthreads();
    sh[tid] += t;
    __syncthreads();
  }
  if (i < N) rowStart[i] = sh[tid] - v;
  if (tid == 255) blockSums[blockIdx.x] = sh[255];
}

__global__ __launch_bounds__(256) void scan_sums(int* __restrict__ bs, int nb) {
  __shared__ int sh[256];
  __shared__ int carryS;
  const int tid = threadIdx.x;
  if (tid == 0) carryS = 0;
  __syncthreads();
  for (int c = 0; c < nb; c += 256) {
    int i = c + tid;
    int v = (i < nb) ? bs[i] : 0;
    sh[tid] = v;
    __syncthreads();
    for (int o = 1; o < 256; o <<= 1) {
      int t = (tid >= o) ? sh[tid - o] : 0;
      __syncthreads();
      sh[tid] += t;
      __syncthreads();
    }
    int carry = carryS;
    if (i < nb) bs[i] = carry + sh[tid] - v;
    int total = sh[255];
    __syncthreads();
    if (tid == 0) carryS = carry + total;
    __syncthreads();
  }
}

__global__ __launch_bounds__(256) void add_offsets(int* __restrict__ rowStart,
                                                   const int* __restrict__ bs,
                                                   int* __restrict__ cursor, int N, int Etot) {
  int i = blockIdx.x * 256 + threadIdx.x;
  if (i == 0) rowStart[N] = Etot;
  if (i >= N) return;
  int r = rowStart[i] + bs[i >> 8];
  rowStart[i] = r;
  cursor[i] = r;
}

// XCD-partitioned scatter: block b -> xcd = b&7 (round-robin dispatch heuristic);
// handles only dsts in that XCD's 1/8 node range so cursor atomics + srcS stores
// stay resident in ONE XCD's L2 (850 KB << 4 MB) -> lines written back once.
// Perf-only assumption; correctness independent of the actual mapping.
#define SCAT_CHUNK 2048
__global__ __launch_bounds__(256) void csr_scatter_x(const int* __restrict__ ei, int E, int Etot,
                                                     int* __restrict__ cursor,
                                                     int* __restrict__ srcS, int nper) {
  const int xcd = blockIdx.x & 7;
  const int lo = xcd * nper;
  const int hi = lo + nper;
  const int e0 = (blockIdx.x >> 3) * SCAT_CHUNK + threadIdx.x;
#pragma unroll
  for (int it = 0; it < SCAT_CHUNK / 256; ++it) {
    int e = e0 + it * 256;
    if (e < Etot) {
      int d = (e < E) ? ei[E + e] : (e - E);
      if (d >= lo && d < hi) {
        int s = (e < E) ? ei[e] : d;
        int pos = atomicAdd(&cursor[d], 1);
        srcS[pos] = s;
      }
    }
  }
}

// ==== fused per-node online-softmax + bf16 gather-aggregate, 16 lanes/node ====
template <int H>
__global__ __launch_bounds__(256) void gat_node(
    const int* __restrict__ rowStart, const int* __restrict__ srcS,
    const float* __restrict__ AS, const float* __restrict__ AD,
    const unsigned short* __restrict__ Hbf, const float* __restrict__ B,
    float* __restrict__ Out, int N) {
  const int n = blockIdx.x * 16 + (threadIdx.x >> 4);
  if (n >= N) return;
  const int l = threadIdx.x & 15;
  const int beg = rowStart[n];
  const int end = rowStart[n + 1];
  const int f0 = l * 8;
  const int myh = (H == 4) ? (l >> 2) : 0;

  float4 adv = make_float4(0.f, 0.f, 0.f, 0.f);
  if (H == 4) adv = *(const float4*)(AD + (size_t)n * 4);
  else adv.x = AD[n];

  float4 m = make_float4(-INFINITY, -INFINITY, -INFINITY, -INFINITY);
  float4 den = make_float4(0.f, 0.f, 0.f, 0.f);
  float acc[8];
#pragma unroll
  for (int k = 0; k < 8; ++k) acc[k] = 0.f;

  for (int base = beg; base < end; base += 16) {
    const int i = base + l;
    int s = 0;
    float4 e = make_float4(-INFINITY, -INFINITY, -INFINITY, -INFINITY);
    if (i < end) {
      s = srcS[i];
      if (H == 4) {
        float4 as = *(const float4*)(AS + (size_t)s * 4);
        e.x = lrelu(as.x + adv.x);
        e.y = lrelu(as.y + adv.y);
        e.z = lrelu(as.z + adv.z);
        e.w = lrelu(as.w + adv.w);
      } else {
        e.x = lrelu(AS[s] + adv.x);
      }
    }
    float4 cm = e;
#pragma unroll
    for (int o = 8; o >= 1; o >>= 1) {
      cm.x = fmaxf(cm.x, __shfl_xor(cm.x, o, 16));
      if (H == 4) {
        cm.y = fmaxf(cm.y, __shfl_xor(cm.y, o, 16));
        cm.z = fmaxf(cm.z, __shfl_xor(cm.z, o, 16));
        cm.w = fmaxf(cm.w, __shfl_xor(cm.w, o, 16));
      }
    }
    float4 mN, rs, p;
    mN.x = fmaxf(m.x, cm.x);
    rs.x = __expf(m.x - mN.x);
    p.x = __expf(e.x - mN.x);
    if (H == 4) {
      mN.y = fmaxf(m.y, cm.y); rs.y = __expf(m.y - mN.y); p.y = __expf(e.y - mN.y);
      mN.z = fmaxf(m.z, cm.z); rs.z = __expf(m.z - mN.z); p.z = __expf(e.z - mN.z);
      mN.w = fmaxf(m.w, cm.w); rs.w = __expf(m.w - mN.w); p.w = __expf(e.w - mN.w);
    }
    m = mN;
    float4 cs = p;
#pragma unroll
    for (int o = 8; o >= 1; o >>= 1) {
      cs.x += __shfl_xor(cs.x, o, 16);
      if (H == 4) {
        cs.y += __shfl_xor(cs.y, o, 16);
        cs.z += __shfl_xor(cs.z, o, 16);
        cs.w += __shfl_xor(cs.w, o, 16);
      }
    }
    den.x = den.x * rs.x + cs.x;
    float accScale = rs.x;
    if (H == 4) {
      den.y = den.y * rs.y + cs.y;
      den.z = den.z * rs.z + cs.z;
      den.w = den.w * rs.w + cs.w;
      accScale = (myh == 0) ? rs.x : (myh == 1) ? rs.y : (myh == 2) ? rs.z : rs.w;
    }
#pragma unroll
    for (int k = 0; k < 8; ++k) acc[k] *= accScale;

    const int cnt = min(16, end - base);
    for (int j = 0; j < cnt; ++j) {
      const int sj = __shfl(s, j, 16);
      float aj;
      if (H == 4) {
        float ax = __shfl(p.x, j, 16);
        float ay = __shfl(p.y, j, 16);
        float az = __shfl(p.z, j, 16);
        float aw = __shfl(p.w, j, 16);
        aj = (myh == 0) ? ax : (myh == 1) ? ay : (myh == 2) ? az : aw;
      } else {
        aj = __shfl(p.x, j, 16);
      }
      const uint4 hv = *(const uint4*)(Hbf + (size_t)sj * 128 + f0);
      acc[0] += __uint_as_float(hv.x << 16) * aj;
      acc[1] += __uint_as_float(hv.x & 0xffff0000u) * aj;
      acc[2] += __uint_as_float(hv.y << 16) * aj;
      acc[3] += __uint_as_float(hv.y & 0xffff0000u) * aj;
      acc[4] += __uint_as_float(hv.z << 16) * aj;
      acc[5] += __uint_as_float(hv.z & 0xffff0000u) * aj;
      acc[6] += __uint_as_float(hv.w << 16) * aj;
      acc[7] += __uint_as_float(hv.w & 0xffff0000u) * aj;
    }
  }
  float denf = den.x;
  if (H == 4) denf = (myh == 0) ? den.x : (myh == 1) ? den.y : (myh == 2) ? den.z : den.w;
  const float inv = 1.0f / (denf + 1e-16f);
  float4 o0, o1;
  o0.x = acc[0] * inv + B[f0 + 0];
  o0.y = acc[1] * inv + B[f0 + 1];
  o0.z = acc[2] * inv + B[f0 + 2];
  o0.w = acc[3] * inv + B[f0 + 3];
  o1.x = acc[4] * inv + B[f0 + 4];
  o1.y = acc[5] * inv + B[f0 + 5];
  o1.z = acc[6] * inv + B[f0 + 6];
  o1.w = acc[7] * inv + B[f0 + 7];
  *(float4*)(Out + (size_t)n * 128 + f0) = o0;
  *(float4*)(Out + (size_t)n * 128 + f0 + 4) = o1;
}

extern "C" void kernel_launch(void* const* d_in, const int* in_sizes, int n_in,
                              void* d_out, int out_size, void* d_ws, size_t ws_size,
                              hipStream_t stream) {
  const float* x    = (const float*)d_in[0];
  const int*   ei   = (const int*)d_in[1];
  const float* W1   = (const float*)d_in[2];
  const float* as1w = (const float*)d_in[3];
  const float* ad1w = (const float*)d_in[4];
  const float* b1   = (const float*)d_in[5];
  const float* W2   = (const float*)d_in[6];
  const float* as2w = (const float*)d_in[7];
  const float* ad2w = (const float*)d_in[8];
  const float* b2   = (const float*)d_in[9];

  const int N = in_sizes[0] / 128;
  const int E = in_sizes[1] / 2;
  const int Etot = E + N;
  const int nb = (N + 255) / 256;

  char* ws = (char*)d_ws;
  size_t off = 0;
  auto alloc = [&](size_t bytes) -> void* {
    void* p = ws + off;
    off = (off + bytes + 255) & ~(size_t)255;
    return p;
  };
  unsigned short* Hbf  = (unsigned short*)alloc((size_t)N * 128 * 2);
  float* out1 = (float*)alloc((size_t)N * 128 * 4);
  float* AS1  = (float*)alloc((size_t)N * 4 * 4);
  float* AD1  = (float*)alloc((size_t)N * 4 * 4);
  float* AS2  = (float*)alloc((size_t)N * 4);
  float* AD2  = (float*)alloc((size_t)N * 4);
  int*   cnt      = (int*)alloc((size_t)N * 4);
  int*   rowStart = (int*)alloc((size_t)(N + 1) * 4);
  int*   cursor   = (int*)alloc((size_t)N * 4);
  int*   blockSums= (int*)alloc((size_t)nb * 4);
  int*   srcS     = (int*)alloc((size_t)Etot * 4);

  // ---- CSR build (once, shared by both layers) ----
  hipMemsetAsync(cnt, 0, (size_t)N * 4, stream);
  const int ebBlocks = (Etot + 255) / 256;
  csr_count<<<ebBlocks, 256, 0, stream>>>(ei, E, Etot, cnt);
  scan_blocks<<<nb, 256, 0, stream>>>(cnt, rowStart, blockSums, N);
  scan_sums<<<1, 256, 0, stream>>>(blockSums, nb);
  add_offsets<<<nb, 256, 0, stream>>>(rowStart, blockSums, cursor, N, Etot);
  const int nper = (N + 7) / 8;
  const int scatBlocks = 8 * ((Etot + SCAT_CHUNK - 1) / SCAT_CHUNK);
  csr_scatter_x<<<scatBlocks, 256, 0, stream>>>(ei, E, Etot, cursor, srcS, nper);

  const int gemmBlocks = (N + 63) / 64;
  const int nodeBlocks = (N + 15) / 16;

  // ---- layer 1 (H=4, C=32) ----
  gemm128_fused<4><<<gemmBlocks, 256, 0, stream>>>(x, W1, as1w, ad1w, Hbf, AS1, AD1, N);
  gat_node<4><<<nodeBlocks, 256, 0, stream>>>(rowStart, srcS, AS1, AD1, Hbf, b1, out1, N);

  // ---- layer 2 (H=1, C=128) ----
  gemm128_fused<1><<<gemmBlocks, 256, 0, stream>>>(out1, W2, as2w, ad2w, Hbf, AS2, AD2, N);
  gat_node<1><<<nodeBlocks, 256, 0, stream>>>(rowStart, srcS, AS2, AD2, Hbf, b2, (float*)d_out, N);
}

// Round 6
// 502.985 us; speedup vs baseline: 4.9895x; 1.0373x over previous
//
#include <hip/hip_runtime.h>
#include <cstdint>
#include <cstddef>

#define NEG_SLOPE 0.2f

typedef __attribute__((ext_vector_type(8))) short short8;
typedef __attribute__((ext_vector_type(4))) float f32x4;

__device__ __forceinline__ float lrelu(float v) { return v > 0.0f ? v : NEG_SLOPE * v; }

__device__ __forceinline__ unsigned short f2bf(float f) {
  unsigned u = __float_as_uint(f);
  unsigned r = (u + 0x7fff + ((u >> 16) & 1)) >> 16;  // RNE
  return (unsigned short)r;
}
__device__ __forceinline__ float bf2f(unsigned short u) {
  return __uint_as_float((unsigned)u << 16);
}

// ---- W convert: WT[n][k] = bf16(W[k][n]) (done once per launch, 64 KB) ----
__global__ __launch_bounds__(256) void wt_convert(const float* __restrict__ W,
                                                  unsigned short* __restrict__ WT) {
  int i = blockIdx.x * 256 + threadIdx.x;
  if (i >= 128 * 128) return;
  int n = i >> 7, k = i & 127;
  WT[i] = f2bf(W[k * 128 + n]);
}

// ---- MFMA GEMM: Ybf[N,128](bf16) = X[N,128](fp32) @ W (WT = bf16, [n][k]) ----
// 64 rows/block, 256 threads = 4 waves; wave w does rows 16w..16w+15, all 8 col tiles.
__global__ __launch_bounds__(256) void gemm_mfma(const float* __restrict__ X,
                                                 const unsigned short* __restrict__ WT,
                                                 unsigned short* __restrict__ Ybf, int N) {
  __shared__ unsigned short xs[64 * 136];   // X tile bf16, stride 136 (272B, 16B-aligned)
  __shared__ unsigned short wsh[128 * 136]; // W^T bf16 [n][k]
  const int tid = threadIdx.x;
  const int rowBase = blockIdx.x * 64;
  const int rowsHere = min(64, N - rowBase);

  // stage WT -> LDS: 128x128 bf16 = 2048 16B-chunks  (ROUND-5 FIX: was 1024 -> half of
  // each row left uninitialized -> NaN)
#pragma unroll
  for (int it = 0; it < 8; ++it) {
    int idx = it * 256 + tid;
    int n = idx >> 4, k16 = idx & 15;
    *(uint4*)(wsh + n * 136 + k16 * 8) = *(const uint4*)(WT + (size_t)n * 128 + k16 * 8);
  }
  // stage X (fp32 -> bf16): 64x128
#pragma unroll
  for (int it = 0; it < 8; ++it) {
    int idx = it * 256 + tid;
    int r = idx >> 5, c4 = idx & 31;
    float4 v = make_float4(0.f, 0.f, 0.f, 0.f);
    if (r < rowsHere) v = *(const float4*)(X + (size_t)(rowBase + r) * 128 + c4 * 4);
    ushort4 bv;
    bv.x = f2bf(v.x); bv.y = f2bf(v.y); bv.z = f2bf(v.z); bv.w = f2bf(v.w);
    *(ushort4*)(xs + r * 136 + c4 * 4) = bv;
  }
  __syncthreads();

  const int lane = tid & 63;
  const int w = tid >> 6;
  const int m15 = lane & 15;
  const int quad = lane >> 4;
  f32x4 acc[8];
#pragma unroll
  for (int t = 0; t < 8; ++t) acc[t] = (f32x4){0.f, 0.f, 0.f, 0.f};

#pragma unroll
  for (int k0 = 0; k0 < 128; k0 += 32) {
    short8 a = *(const short8*)(xs + (16 * w + m15) * 136 + k0 + quad * 8);
#pragma unroll
    for (int t = 0; t < 8; ++t) {
      short8 b = *(const short8*)(wsh + (t * 16 + m15) * 136 + k0 + quad * 8);
      acc[t] = __builtin_amdgcn_mfma_f32_16x16x32_bf16(a, b, acc[t], 0, 0, 0);
    }
  }

  // epilogue: acc -> LDS (bf16) -> coalesced global store
  __syncthreads();
#pragma unroll
  for (int t = 0; t < 8; ++t) {
#pragma unroll
    for (int r = 0; r < 4; ++r) {
      int row = 16 * w + quad * 4 + r;  // C/D layout: col=lane&15, row=quad*4+reg
      xs[row * 136 + t * 16 + m15] = f2bf(acc[t][r]);
    }
  }
  __syncthreads();
#pragma unroll
  for (int it = 0; it < 4; ++it) {
    int idx = it * 256 + tid;  // 64 rows x 16 chunks of 16B
    int r = idx >> 4, c8 = idx & 15;
    if (r < rowsHere)
      *(uint4*)(Ybf + (size_t)(rowBase + r) * 128 + c8 * 8) = *(const uint4*)(xs + r * 136 + c8 * 8);
  }
}

// ---- alphas from bf16 h: H=4 (16 lanes per (n,h)) ----
__global__ __launch_bounds__(256) void alphas_h4_bf(const unsigned short* __restrict__ Hbf,
    const float* __restrict__ Asrc, const float* __restrict__ Adst,
    float* __restrict__ AS, float* __restrict__ AD, int N) {
  const int tid = threadIdx.x;
  const int g = blockIdx.x * 16 + (tid >> 4);  // g = n*4 + h
  if (g >= N * 4) return;
  const int c = tid & 15;
  const int h = g & 3;
  unsigned u = *(const unsigned*)(Hbf + (size_t)g * 32 + c * 2);
  float v0 = bf2f((unsigned short)u), v1 = bf2f((unsigned short)(u >> 16));
  float as = v0 * Asrc[h * 32 + 2 * c] + v1 * Asrc[h * 32 + 2 * c + 1];
  float ad = v0 * Adst[h * 32 + 2 * c] + v1 * Adst[h * 32 + 2 * c + 1];
#pragma unroll
  for (int o = 8; o >= 1; o >>= 1) {
    as += __shfl_xor(as, o, 16);
    ad += __shfl_xor(ad, o, 16);
  }
  if (c == 0) { AS[g] = as; AD[g] = ad; }
}

// ---- alphas from bf16 h: H=1 (64 lanes per node, 2 elems/lane) ----
__global__ __launch_bounds__(256) void alphas_h1_bf(const unsigned short* __restrict__ Hbf,
    const float* __restrict__ Asrc, const float* __restrict__ Adst,
    float* __restrict__ AS, float* __restrict__ AD, int N) {
  const int tid = threadIdx.x;
  const int n = blockIdx.x * 4 + (tid >> 6);
  if (n >= N) return;
  const int lane = tid & 63;
  unsigned u = *(const unsigned*)(Hbf + (size_t)n * 128 + lane * 2);
  float v0 = bf2f((unsigned short)u), v1 = bf2f((unsigned short)(u >> 16));
  float as = v0 * Asrc[2 * lane] + v1 * Asrc[2 * lane + 1];
  float ad = v0 * Adst[2 * lane] + v1 * Adst[2 * lane + 1];
#pragma unroll
  for (int o = 32; o >= 1; o >>= 1) {
    as += __shfl_xor(as, o, 64);
    ad += __shfl_xor(ad, o, 64);
  }
  if (lane == 0) { AS[n] = as; AD[n] = ad; }
}

// ================= CSR build =================
__global__ __launch_bounds__(256) void csr_count(const int* __restrict__ ei, int E, int Etot,
                                                 int* __restrict__ cnt) {
  int e = blockIdx.x * 256 + threadIdx.x;
  if (e >= Etot) return;
  int d = (e < E) ? ei[E + e] : (e - E);
  atomicAdd(&cnt[d], 1);
}

__global__ __launch_bounds__(256) void scan_blocks(const int* __restrict__ cnt,
                                                   int* __restrict__ rowStart,
                                                   int* __restrict__ blockSums, int N) {
  __shared__ int sh[256];
  const int tid = threadIdx.x;
  const int i = blockIdx.x * 256 + tid;
  int v = (i < N) ? cnt[i] : 0;
  sh[tid] = v;
  __syncthreads();
  for (int o = 1; o < 256; o <<= 1) {
    int t = (tid >= o) ? sh[tid - o] : 0;
    __syncthreads();
    sh[tid] += t;
    __syncthreads();
  }
  if (i < N) rowStart[i] = sh[tid] - v;
  if (tid == 255) blockSums[blockIdx.x] = sh[255];
}

__global__ __launch_bounds__(256) void scan_sums(int* __restrict__ bs, int nb) {
  __shared__ int sh[256];
  __shared__ int carryS;
  const int tid = threadIdx.x;
  if (tid == 0) carryS = 0;
  __syncthreads();
  for (int c = 0; c < nb; c += 256) {
    int i = c + tid;
    int v = (i < nb) ? bs[i] : 0;
    sh[tid] = v;
    __syncthreads();
    for (int o = 1; o < 256; o <<= 1) {
      int t = (tid >= o) ? sh[tid - o] : 0;
      __syncthreads();
      sh[tid] += t;
      __syncthreads();
    }
    int carry = carryS;
    if (i < nb) bs[i] = carry + sh[tid] - v;
    int total = sh[255];
    __syncthreads();
    if (tid == 0) carryS = carry + total;
    __syncthreads();
  }
}

__global__ __launch_bounds__(256) void add_offsets(int* __restrict__ rowStart,
                                                   const int* __restrict__ bs,
                                                   int* __restrict__ cursor, int N, int Etot) {
  int i = blockIdx.x * 256 + threadIdx.x;
  if (i == 0) rowStart[N] = Etot;
  if (i >= N) return;
  int r = rowStart[i] + bs[i >> 8];
  rowStart[i] = r;
  cursor[i] = r;
}

// XCD-partitioned scatter (round 3): perf-only heuristic, G16-safe.
#define SCAT_CHUNK 2048
__global__ __launch_bounds__(256) void csr_scatter_x(const int* __restrict__ ei, int E, int Etot,
                                                     int* __restrict__ cursor,
                                                     int* __restrict__ srcS, int nper) {
  const int xcd = blockIdx.x & 7;
  const int lo = xcd * nper;
  const int hi = lo + nper;
  const int e0 = (blockIdx.x >> 3) * SCAT_CHUNK + threadIdx.x;
#pragma unroll
  for (int it = 0; it < SCAT_CHUNK / 256; ++it) {
    int e = e0 + it * 256;
    if (e < Etot) {
      int d = (e < E) ? ei[E + e] : (e - E);
      if (d >= lo && d < hi) {
        int s = (e < E) ? ei[e] : d;
        int pos = atomicAdd(&cursor[d], 1);
        srcS[pos] = s;
      }
    }
  }
}

// ==== fused per-node online-softmax + bf16 gather-aggregate, 16 lanes/node ====
// Full chunks: (s,p) staged via LDS (no bpermute storm), gathers batched 8-deep.
template <int H>
__global__ __launch_bounds__(256) void gat_node(
    const int* __restrict__ rowStart, const int* __restrict__ srcS,
    const float* __restrict__ AS, const float* __restrict__ AD,
    const unsigned short* __restrict__ Hbf, const float* __restrict__ B,
    float* __restrict__ Out, int N) {
  __shared__ int sh_s[16][16];
  __shared__ float sh_p[16][68];  // stride 68 floats = 272B (16B-aligned, bank-spread)
  const int g = threadIdx.x >> 4;
  const int n = blockIdx.x * 16 + g;
  if (n >= N) return;
  const int l = threadIdx.x & 15;
  const int beg = rowStart[n];
  const int end = rowStart[n + 1];
  const int f0 = l * 8;
  const int myh = (H == 4) ? (l >> 2) : 0;

  float4 adv = make_float4(0.f, 0.f, 0.f, 0.f);
  if (H == 4) adv = *(const float4*)(AD + (size_t)n * 4);
  else adv.x = AD[n];

  float4 m = make_float4(-INFINITY, -INFINITY, -INFINITY, -INFINITY);
  float4 den = make_float4(0.f, 0.f, 0.f, 0.f);
  float acc[8];
#pragma unroll
  for (int k = 0; k < 8; ++k) acc[k] = 0.f;

  int base = beg;
  // ---------- full 16-edge chunks ----------
  for (; base + 16 <= end; base += 16) {
    const int s = srcS[base + l];
    float4 e, p, cm, mN, rs, cs;
    if (H == 4) {
      float4 as = *(const float4*)(AS + (size_t)s * 4);
      e.x = lrelu(as.x + adv.x);
      e.y = lrelu(as.y + adv.y);
      e.z = lrelu(as.z + adv.z);
      e.w = lrelu(as.w + adv.w);
    } else {
      e.x = lrelu(AS[s] + adv.x);
    }
    cm = e;
#pragma unroll
    for (int o = 8; o >= 1; o >>= 1) {
      cm.x = fmaxf(cm.x, __shfl_xor(cm.x, o, 16));
      if (H == 4) {
        cm.y = fmaxf(cm.y, __shfl_xor(cm.y, o, 16));
        cm.z = fmaxf(cm.z, __shfl_xor(cm.z, o, 16));
        cm.w = fmaxf(cm.w, __shfl_xor(cm.w, o, 16));
      }
    }
    mN.x = fmaxf(m.x, cm.x); rs.x = __expf(m.x - mN.x); p.x = __expf(e.x - mN.x);
    if (H == 4) {
      mN.y = fmaxf(m.y, cm.y); rs.y = __expf(m.y - mN.y); p.y = __expf(e.y - mN.y);
      mN.z = fmaxf(m.z, cm.z); rs.z = __expf(m.z - mN.z); p.z = __expf(e.z - mN.z);
      mN.w = fmaxf(m.w, cm.w); rs.w = __expf(m.w - mN.w); p.w = __expf(e.w - mN.w);
    }
    m = mN;
    cs = p;
#pragma unroll
    for (int o = 8; o >= 1; o >>= 1) {
      cs.x += __shfl_xor(cs.x, o, 16);
      if (H == 4) {
        cs.y += __shfl_xor(cs.y, o, 16);
        cs.z += __shfl_xor(cs.z, o, 16);
        cs.w += __shfl_xor(cs.w, o, 16);
      }
    }
    den.x = den.x * rs.x + cs.x;
    float accScale = rs.x;
    if (H == 4) {
      den.y = den.y * rs.y + cs.y;
      den.z = den.z * rs.z + cs.z;
      den.w = den.w * rs.w + cs.w;
      accScale = (myh == 0) ? rs.x : (myh == 1) ? rs.y : (myh == 2) ? rs.z : rs.w;
    }
#pragma unroll
    for (int k = 0; k < 8; ++k) acc[k] *= accScale;

    // stage (s, p) to LDS (wave-synchronous within group; no barrier needed)
    sh_s[g][l] = s;
    if (H == 4) *(float4*)(&sh_p[g][l * 4]) = p;
    else sh_p[g][l] = p.x;

    // batched gather: 8 loads in flight before first use
#pragma unroll
    for (int half = 0; half < 2; ++half) {
      uint4 hv[8];
#pragma unroll
      for (int q = 0; q < 8; ++q) {
        int sj = sh_s[g][half * 8 + q];
        hv[q] = *(const uint4*)(Hbf + (size_t)sj * 128 + f0);
      }
#pragma unroll
      for (int q = 0; q < 8; ++q) {
        float aj = (H == 4) ? sh_p[g][(half * 8 + q) * 4 + myh] : sh_p[g][half * 8 + q];
        acc[0] += bf2f((unsigned short)hv[q].x) * aj;
        acc[1] += bf2f((unsigned short)(hv[q].x >> 16)) * aj;
        acc[2] += bf2f((unsigned short)hv[q].y) * aj;
        acc[3] += bf2f((unsigned short)(hv[q].y >> 16)) * aj;
        acc[4] += bf2f((unsigned short)hv[q].z) * aj;
        acc[5] += bf2f((unsigned short)(hv[q].z >> 16)) * aj;
        acc[6] += bf2f((unsigned short)hv[q].w) * aj;
        acc[7] += bf2f((unsigned short)(hv[q].w >> 16)) * aj;
      }
    }
  }

  // ---------- tail chunk (<16 edges): shfl path ----------
  if (base < end) {
    const int i = base + l;
    int s = 0;
    float4 e = make_float4(-INFINITY, -INFINITY, -INFINITY, -INFINITY);
    if (i < end) {
      s = srcS[i];
      if (H == 4) {
        float4 as = *(const float4*)(AS + (size_t)s * 4);
        e.x = lrelu(as.x + adv.x);
        e.y = lrelu(as.y + adv.y);
        e.z = lrelu(as.z + adv.z);
        e.w = lrelu(as.w + adv.w);
      } else {
        e.x = lrelu(AS[s] + adv.x);
      }
    }
    float4 cm = e;
#pragma unroll
    for (int o = 8; o >= 1; o >>= 1) {
      cm.x = fmaxf(cm.x, __shfl_xor(cm.x, o, 16));
      if (H == 4) {
        cm.y = fmaxf(cm.y, __shfl_xor(cm.y, o, 16));
        cm.z = fmaxf(cm.z, __shfl_xor(cm.z, o, 16));
        cm.w = fmaxf(cm.w, __shfl_xor(cm.w, o, 16));
      }
    }
    float4 mN, rs, p;
    mN.x = fmaxf(m.x, cm.x); rs.x = __expf(m.x - mN.x); p.x = __expf(e.x - mN.x);
    if (H == 4) {
      mN.y = fmaxf(m.y, cm.y); rs.y = __expf(m.y - mN.y); p.y = __expf(e.y - mN.y);
      mN.z = fmaxf(m.z, cm.z); rs.z = __expf(m.z - mN.z); p.z = __expf(e.z - mN.z);
      mN.w = fmaxf(m.w, cm.w); rs.w = __expf(m.w - mN.w); p.w = __expf(e.w - mN.w);
    }
    m = mN;
    float4 cs = p;
#pragma unroll
    for (int o = 8; o >= 1; o >>= 1) {
      cs.x += __shfl_xor(cs.x, o, 16);
      if (H == 4) {
        cs.y += __shfl_xor(cs.y, o, 16);
        cs.z += __shfl_xor(cs.z, o, 16);
        cs.w += __shfl_xor(cs.w, o, 16);
      }
    }
    den.x = den.x * rs.x + cs.x;
    float accScale = rs.x;
    if (H == 4) {
      den.y = den.y * rs.y + cs.y;
      den.z = den.z * rs.z + cs.z;
      den.w = den.w * rs.w + cs.w;
      accScale = (myh == 0) ? rs.x : (myh == 1) ? rs.y : (myh == 2) ? rs.z : rs.w;
    }
#pragma unroll
    for (int k = 0; k < 8; ++k) acc[k] *= accScale;

    const int cnt = end - base;
    for (int j = 0; j < cnt; ++j) {
      const int sj = __shfl(s, j, 16);
      float aj;
      if (H == 4) {
        float ax = __shfl(p.x, j, 16);
        float ay = __shfl(p.y, j, 16);
        float az = __shfl(p.z, j, 16);
        float aw = __shfl(p.w, j, 16);
        aj = (myh == 0) ? ax : (myh == 1) ? ay : (myh == 2) ? az : aw;
      } else {
        aj = __shfl(p.x, j, 16);
      }
      const uint4 hv = *(const uint4*)(Hbf + (size_t)sj * 128 + f0);
      acc[0] += bf2f((unsigned short)hv.x) * aj;
      acc[1] += bf2f((unsigned short)(hv.x >> 16)) * aj;
      acc[2] += bf2f((unsigned short)hv.y) * aj;
      acc[3] += bf2f((unsigned short)(hv.y >> 16)) * aj;
      acc[4] += bf2f((unsigned short)hv.z) * aj;
      acc[5] += bf2f((unsigned short)(hv.z >> 16)) * aj;
      acc[6] += bf2f((unsigned short)hv.w) * aj;
      acc[7] += bf2f((unsigned short)(hv.w >> 16)) * aj;
    }
  }

  float denf = den.x;
  if (H == 4) denf = (myh == 0) ? den.x : (myh == 1) ? den.y : (myh == 2) ? den.z : den.w;
  const float inv = 1.0f / (denf + 1e-16f);
  float4 o0, o1;
  o0.x = acc[0] * inv + B[f0 + 0];
  o0.y = acc[1] * inv + B[f0 + 1];
  o0.z = acc[2] * inv + B[f0 + 2];
  o0.w = acc[3] * inv + B[f0 + 3];
  o1.x = acc[4] * inv + B[f0 + 4];
  o1.y = acc[5] * inv + B[f0 + 5];
  o1.z = acc[6] * inv + B[f0 + 6];
  o1.w = acc[7] * inv + B[f0 + 7];
  *(float4*)(Out + (size_t)n * 128 + f0) = o0;
  *(float4*)(Out + (size_t)n * 128 + f0 + 4) = o1;
}

extern "C" void kernel_launch(void* const* d_in, const int* in_sizes, int n_in,
                              void* d_out, int out_size, void* d_ws, size_t ws_size,
                              hipStream_t stream) {
  const float* x    = (const float*)d_in[0];
  const int*   ei   = (const int*)d_in[1];
  const float* W1   = (const float*)d_in[2];
  const float* as1w = (const float*)d_in[3];
  const float* ad1w = (const float*)d_in[4];
  const float* b1   = (const float*)d_in[5];
  const float* W2   = (const float*)d_in[6];
  const float* as2w = (const float*)d_in[7];
  const float* ad2w = (const float*)d_in[8];
  const float* b2   = (const float*)d_in[9];

  const int N = in_sizes[0] / 128;
  const int E = in_sizes[1] / 2;
  const int Etot = E + N;
  const int nb = (N + 255) / 256;

  char* ws = (char*)d_ws;
  size_t off = 0;
  auto alloc = [&](size_t bytes) -> void* {
    void* p = ws + off;
    off = (off + bytes + 255) & ~(size_t)255;
    return p;
  };
  unsigned short* Hbf  = (unsigned short*)alloc((size_t)N * 128 * 2);
  float* out1 = (float*)alloc((size_t)N * 128 * 4);
  float* AS1  = (float*)alloc((size_t)N * 4 * 4);
  float* AD1  = (float*)alloc((size_t)N * 4 * 4);
  float* AS2  = (float*)alloc((size_t)N * 4);
  float* AD2  = (float*)alloc((size_t)N * 4);
  unsigned short* WT1 = (unsigned short*)alloc(128 * 128 * 2);
  unsigned short* WT2 = (unsigned short*)alloc(128 * 128 * 2);
  int*   cnt      = (int*)alloc((size_t)N * 4);
  int*   rowStart = (int*)alloc((size_t)(N + 1) * 4);
  int*   cursor   = (int*)alloc((size_t)N * 4);
  int*   blockSums= (int*)alloc((size_t)nb * 4);
  int*   srcS     = (int*)alloc((size_t)Etot * 4);

  // ---- weight convert (tiny) ----
  wt_convert<<<64, 256, 0, stream>>>(W1, WT1);
  wt_convert<<<64, 256, 0, stream>>>(W2, WT2);

  // ---- CSR build (once, shared by both layers) ----
  hipMemsetAsync(cnt, 0, (size_t)N * 4, stream);
  const int ebBlocks = (Etot + 255) / 256;
  csr_count<<<ebBlocks, 256, 0, stream>>>(ei, E, Etot, cnt);
  scan_blocks<<<nb, 256, 0, stream>>>(cnt, rowStart, blockSums, N);
  scan_sums<<<1, 256, 0, stream>>>(blockSums, nb);
  add_offsets<<<nb, 256, 0, stream>>>(rowStart, blockSums, cursor, N, Etot);
  const int nper = (N + 7) / 8;
  const int scatBlocks = 8 * ((Etot + SCAT_CHUNK - 1) / SCAT_CHUNK);
  csr_scatter_x<<<scatBlocks, 256, 0, stream>>>(ei, E, Etot, cursor, srcS, nper);

  const int gemmBlocks = (N + 63) / 64;
  const int nodeBlocks = (N + 15) / 16;

  // ---- layer 1 (H=4, C=32) ----
  gemm_mfma<<<gemmBlocks, 256, 0, stream>>>(x, WT1, Hbf, N);
  alphas_h4_bf<<<(N * 4 + 15) / 16, 256, 0, stream>>>(Hbf, as1w, ad1w, AS1, AD1, N);
  gat_node<4><<<nodeBlocks, 256, 0, stream>>>(rowStart, srcS, AS1, AD1, Hbf, b1, out1, N);

  // ---- layer 2 (H=1, C=128) ----
  gemm_mfma<<<gemmBlocks, 256, 0, stream>>>(out1, WT2, Hbf, N);
  alphas_h1_bf<<<(N + 3) / 4, 256, 0, stream>>>(Hbf, as2w, ad2w, AS2, AD2, N);
  gat_node<1><<<nodeBlocks, 256, 0, stream>>>(rowStart, srcS, AS2, AD2, Hbf, b2, (float*)d_out, N);
}